// Round 9
// baseline (762.459 us; speedup 1.0000x reference)
//
// v8 (identical algorithm to v3-v7; resubmitted after repeated GPU-broker capacity timeouts)
#include <hip/hip_runtime.h>
#include <hip/hip_bf16.h>
#include <math.h>

#define NUM_CLASSES 21
#define NCM1        20      // classes minus background
#define TOP_K       200
#define K_CAND      400
#define NMS_THRESH  0.45f
#define CONF_THRESH 0.01f
#define VAR0        0.1f
#define VAR1        0.2f
#define P           24564
#define BS          16

#define MASK_W      7       // ceil(400/64)
#define CAND_CAP    1024
#define T0          0.97f   // prefilter threshold; exact-top400 guaranteed when
                            // 400 <= count(s>=T0) <= 1024, else exact fallback path

typedef unsigned long long u64;
typedef unsigned int u32;

// ---------------- K-1: zero the 320 per-task candidate counters ----------------
__global__ __launch_bounds__(512) void k_zero(u32* __restrict__ ccnt) {
    int i = threadIdx.x;
    if (i < BS * NCM1) ccnt[i] = 0;
}

// ---------------- K0: coalesced prefilter scan of conf [B,P,21] ----------------
// Each thread handles 4 consecutive floats (float4). Scores >= T0 are appended
// to the per-(image,class) candidate list as composite keys (bits<<32)|~prior.
__global__ __launch_bounds__(256) void k_collect(const float* __restrict__ conf,
                                                 u64* __restrict__ cl,
                                                 u32* __restrict__ ccnt) {
    const int t = blockIdx.x * 256 + threadIdx.x;
    const int total4 = BS * P * NUM_CLASSES / 4;   // divides exactly
    if (t >= total4) return;
    float4 v = ((const float4*)conf)[t];
    float vv[4] = {v.x, v.y, v.z, v.w};
#pragma unroll
    for (int j = 0; j < 4; ++j) {
        float s = vv[j];
        if (s >= T0) {
            int e = 4 * t + j;
            int c = e % NUM_CLASSES;               // magic-mul divmod
            if (c == 0) continue;                  // background
            int bp = e / NUM_CLASSES;              // b*P + p
            int b = bp / P;
            int p = bp - b * P;
            int task = b * NCM1 + (c - 1);
            u32 pos = atomicAdd(&ccnt[task], 1u);
            if (pos < CAND_CAP)
                cl[(size_t)task * CAND_CAP + pos] =
                    ((u64)__float_as_uint(s) << 32) | (u32)(~(u32)p);
        }
    }
}

// ---------------- K1: per-(image,class) sort + NMS ----------------
__global__ __launch_bounds__(1024) void k_nms(
    const float* __restrict__ loc, const float* __restrict__ priors,
    const float* __restrict__ conf,
    const u64* __restrict__ cl, const u32* __restrict__ ccnt,
    float* __restrict__ dets, int* __restrict__ counts) {

    const int tid = threadIdx.x;
    const int task = blockIdx.x;            // 0..319
    const int b = task / NCM1, c0 = task - b * NCM1;

    __shared__ u64 cand[CAND_CAP];
    __shared__ float sx1[K_CAND], sy1[K_CAND], sx2[K_CAND], sy2[K_CAND];
    __shared__ float sar[K_CAND], ssc[K_CAND];
    __shared__ unsigned char sval[K_CAND];
    __shared__ u64 iou_mask[K_CAND][MASK_W];
    __shared__ u64 kept_w[MASK_W];
    __shared__ int s_cnt;
    __shared__ u32 hist[4][256];
    __shared__ u32 suf[256];
    __shared__ u32 s_cut, s_k, s_ncand;

    const u32 n = ccnt[task];               // block-uniform
    u32 ncand;

    if (n >= K_CAND && n <= CAND_CAP) {
        // ---- fast path: prefilter list provably contains the exact top-400 ----
        const u64* src = cl + (size_t)task * CAND_CAP;
        for (int i = tid; i < CAND_CAP; i += 1024)
            cand[i] = ((u32)i < n) ? src[i] : 0ull;
        ncand = n;
        __syncthreads();
    } else {
        // ---- exact fallback: 4-round MSB radix select, strided conf reads ----
        const float* sp = conf + (size_t)b * P * NUM_CLASSES + (c0 + 1);
        u32 prefix = 0, k = K_CAND;
        const int wv = (tid >> 6) & 3;
        for (int round = 0; round < 4; ++round) {
            if (tid < 256) { hist[0][tid] = 0; hist[1][tid] = 0;
                             hist[2][tid] = 0; hist[3][tid] = 0; }
            __syncthreads();
            const int msb = 8 * round;
            const int dsh = 24 - msb;
            for (int p = tid; p < P; p += 1024) {
                u32 u = __float_as_uint(sp[(size_t)p * NUM_CLASSES]);
                bool match = (round == 0) || ((u >> (32 - msb)) == prefix);
                if (match) atomicAdd(&hist[wv][(u >> dsh) & 0xFF], 1u);
            }
            __syncthreads();
            if (tid < 256)
                suf[tid] = hist[0][tid] + hist[1][tid] + hist[2][tid] + hist[3][tid];
            __syncthreads();
            for (int off = 1; off < 256; off <<= 1) {
                u32 v = 0;
                if (tid < 256) v = suf[tid] + ((tid + off < 256) ? suf[tid + off] : 0u);
                __syncthreads();
                if (tid < 256) suf[tid] = v;
                __syncthreads();
            }
            if (tid < 256 && suf[tid] >= k && (tid == 255 || suf[tid + 1] < k)) {
                s_cut = (u32)tid;
                s_k = k - ((tid == 255) ? 0u : suf[tid + 1]);
            }
            __syncthreads();
            prefix = (prefix << 8) | s_cut;
            k = s_k;
            __syncthreads();
        }
        const u32 V = prefix;
        if (tid == 0) s_ncand = 0;
        __syncthreads();
        for (int p = tid; p < P; p += 1024) {
            u32 u = __float_as_uint(sp[(size_t)p * NUM_CLASSES]);
            if (u >= V) {
                u32 pos = atomicAdd(&s_ncand, 1u);
                if (pos < CAND_CAP) cand[pos] = ((u64)u << 32) | (u32)(~(u32)p);
            }
        }
        __syncthreads();
        ncand = min(s_ncand, (u32)CAND_CAP);
        for (u32 i = ncand + tid; i < CAND_CAP; i += 1024) cand[i] = 0ull;
        __syncthreads();
    }

    // ---- bitonic sort CAND_CAP descending (score desc, prior-idx asc) ----
    for (u32 ksz = 2; ksz <= CAND_CAP; ksz <<= 1) {
        for (u32 j = ksz >> 1; j > 0; j >>= 1) {
            if (tid < CAND_CAP / 2) {
                u32 i = 2 * tid - (tid & (j - 1));
                u32 ixj = i | j;
                u64 a = cand[i], c = cand[ixj];
                bool up = ((i & ksz) == 0);
                if (up ? (a < c) : (a > c)) { cand[i] = c; cand[ixj] = a; }
            }
            __syncthreads();
        }
    }

    // ---- decode top-400 candidate boxes (reference op order) ----
    for (int r = tid; r < K_CAND; r += 1024) {
        if ((u32)r < ncand) {
            u64 key = cand[r];
            u32 idx = ~(u32)key;
            float sc = __uint_as_float((u32)(key >> 32));
            float4 lc = ((const float4*)loc)[(size_t)b * P + idx];
            float4 pr = ((const float4*)priors)[idx];
            float cx = pr.x + lc.x * VAR0 * pr.z;
            float cy = pr.y + lc.y * VAR0 * pr.w;
            float w  = pr.z * expf(lc.z * VAR1);
            float h  = pr.w * expf(lc.w * VAR1);
            float x1 = cx - w * 0.5f, y1 = cy - h * 0.5f;
            float x2 = x1 + w, y2 = y1 + h;
            sx1[r] = x1; sy1[r] = y1; sx2[r] = x2; sy2[r] = y2;
            sar[r] = (x2 - x1) * (y2 - y1);
            ssc[r] = sc;
            sval[r] = (sc > CONF_THRESH) ? 1 : 0;
        } else {
            sx1[r] = 0; sy1[r] = 0; sx2[r] = 0; sy2[r] = 0;
            sar[r] = 0; ssc[r] = 0; sval[r] = 0;
        }
    }
    __syncthreads();

    // ---- 400x400 IoU>thresh bitmask ----
    for (int t = tid; t < K_CAND * MASK_W; t += 1024) {
        int i = t / MASK_W, w = t - i * MASK_W;
        float ix1 = sx1[i], iy1 = sy1[i], ix2 = sx2[i], iy2 = sy2[i], iar = sar[i];
        u64 m = 0;
        int j0 = w * 64;
        int jend = j0 + 64; if (jend > K_CAND) jend = K_CAND;
        for (int j = j0; j < jend; ++j) {
            float xx1 = fmaxf(ix1, sx1[j]);
            float yy1 = fmaxf(iy1, sy1[j]);
            float xx2 = fminf(ix2, sx2[j]);
            float yy2 = fminf(iy2, sy2[j]);
            float iw = fmaxf(xx2 - xx1, 0.0f);
            float ih = fmaxf(yy2 - yy1, 0.0f);
            float inter = iw * ih;
            float uni = iar + sar[j] - inter;
            float iou = inter / fmaxf(uni, 1e-9f);
            if (iou > NMS_THRESH) m |= (1ull << (j - j0));
        }
        iou_mask[i][w] = m;
    }
    __syncthreads();

    // ---- greedy NMS, single wave; lane l holds kept-word l ----
    if (tid < 64) {
        int l = tid;
        u64 kw = 0;
        int cnt = 0;
        for (int i = 0; i < K_CAND; ++i) {
            if (!sval[i]) break;                       // scores desc => valid is a prefix
            u64 mm = (l < MASK_W) ? iou_mask[i][l] : 0ull;
            bool sup = __any((kw & mm) != 0ull);
            if (!sup && cnt < TOP_K) {
                if (l == (i >> 6)) kw |= (1ull << (i & 63));
                ++cnt;
                if (cnt >= TOP_K) break;
            }
        }
        if (l < MASK_W) kept_w[l] = kw;
        if (l == 0) s_cnt = cnt;
    }
    __syncthreads();

    // ---- compact kept (score order == index order) into dets ----
    for (int i = tid; i < K_CAND; i += 1024) {
        u64 w = kept_w[i >> 6];
        if ((w >> (i & 63)) & 1ull) {
            int rank = 0;
            for (int q = 0; q < (i >> 6); ++q) rank += __popcll(kept_w[q]);
            rank += __popcll(w & ((1ull << (i & 63)) - 1ull));
            float* dst = dets + ((size_t)task * TOP_K + rank) * 6;
            dst[0] = sx1[i]; dst[1] = sy1[i]; dst[2] = sx2[i]; dst[3] = sy2[i];
            dst[4] = ssc[i]; dst[5] = (float)(c0 + 1);
        }
    }
    if (tid == 0) counts[task] = s_cnt;
}

// ---------------- K2: per-image global sort of 4000 slots -> output ----------------
#define NSLOT (NCM1 * TOP_K)         // 4000
#define NSORT 4096
#define OUTR  (NUM_CLASSES * TOP_K)  // 4200

__global__ __launch_bounds__(1024) void k_final(const float* __restrict__ dets,
                                                const int* __restrict__ counts,
                                                float* __restrict__ out) {
    const int b = blockIdx.x, tid = threadIdx.x;
    __shared__ u64 key[NSORT];

    for (int f = tid; f < NSORT; f += 1024) {
        u64 kk = 0;
        if (f < NSLOT) {
            int c0 = f / TOP_K, slot = f - c0 * TOP_K;
            if (slot < counts[b * NCM1 + c0]) {
                float sc = dets[((size_t)(b * NCM1 + c0) * TOP_K + slot) * 6 + 4];
                kk = ((u64)__float_as_uint(sc) << 32) | (u32)(~(u32)f);
            }
        }
        key[f] = kk;
    }
    __syncthreads();

    for (u32 ksz = 2; ksz <= NSORT; ksz <<= 1) {
        for (u32 j = ksz >> 1; j > 0; j >>= 1) {
            for (u32 t = tid; t < NSORT / 2; t += 1024) {
                u32 i = 2 * t - (t & (j - 1));
                u32 ixj = i | j;
                u64 a = key[i], c = key[ixj];
                bool up = ((i & ksz) == 0);
                if (up ? (a < c) : (a > c)) { key[i] = c; key[ixj] = a; }
            }
            __syncthreads();
        }
    }

    for (int r = tid; r < OUTR; r += 1024) {
        float o0 = 0, o1 = 0, o2 = 0, o3 = 0, o4 = 0, o5 = 0;
        if (r < NSORT) {
            u64 kk = key[r];
            if (kk) {
                int f = (int)(~(u32)kk);
                int c0 = f / TOP_K, slot = f - c0 * TOP_K;
                const float* src = dets + ((size_t)(b * NCM1 + c0) * TOP_K + slot) * 6;
                o0 = src[0]; o1 = src[1]; o2 = src[2];
                o3 = src[3]; o4 = src[4]; o5 = src[5];
            }
        }
        float* dst = out + ((size_t)b * OUTR + r) * 6;
        dst[0] = o0; dst[1] = o1; dst[2] = o2; dst[3] = o3; dst[4] = o4; dst[5] = o5;
    }
}

extern "C" void kernel_launch(void* const* d_in, const int* in_sizes, int n_in,
                              void* d_out, int out_size, void* d_ws, size_t ws_size,
                              hipStream_t stream) {
    const float* loc    = (const float*)d_in[0];
    const float* conf   = (const float*)d_in[1];
    const float* priors = (const float*)d_in[2];
    float* out = (float*)d_out;

    size_t off = 0;
    u32* ccnt = (u32*)((char*)d_ws + off);
    off += (size_t)BS * NCM1 * sizeof(u32);
    off = (off + 255) & ~(size_t)255;
    u64* cl = (u64*)((char*)d_ws + off);
    off += (size_t)BS * NCM1 * CAND_CAP * sizeof(u64);      // 2.62 MB
    float* dets = (float*)((char*)d_ws + off);
    off += (size_t)BS * NCM1 * TOP_K * 6 * sizeof(float);   // 1.54 MB
    int* counts = (int*)((char*)d_ws + off);

    k_zero<<<1, 512, 0, stream>>>(ccnt);
    int total4 = BS * P * NUM_CLASSES / 4;
    k_collect<<<(total4 + 255) / 256, 256, 0, stream>>>(conf, cl, ccnt);
    k_nms<<<BS * NCM1, 1024, 0, stream>>>(loc, priors, conf, cl, ccnt, dets, counts);
    k_final<<<BS, 1024, 0, stream>>>(dets, counts, out);
}

// Round 11
// 354.420 us; speedup vs baseline: 2.1513x; 2.1513x over previous
//
// v10 (identical to v9; resubmitted after GPU-broker capacity timeout)
#include <hip/hip_runtime.h>
#include <hip/hip_bf16.h>
#include <math.h>

#define NUM_CLASSES 21
#define NCM1        20      // classes minus background
#define TOP_K       200
#define K_CAND      400
#define NMS_THRESH  0.45f
#define CONF_THRESH 0.01f
#define VAR0        0.1f
#define VAR1        0.2f
#define P           24564
#define BS          16

#define MASK_W      7       // ceil(400/64)
#define CAND_CAP    1024
#define T0          0.97f   // prefilter threshold; exact-top400 guaranteed when
                            // 400 <= count(s>=T0) <= 1024, else exact fallback path

#define NTASK       (BS * NCM1)            // 320
#define CPAD        16                     // ccnt stride in u32 = 64B (one cache line per counter)
#define TOTAL4      (BS * P * NUM_CLASSES / 4)   // 2,063,376 (divides exactly)
#define CBLK        1280                   // collect blocks
#define CCHUNK      ((TOTAL4 + CBLK - 1) / CBLK) // float4s per collect block
#define STAGE_CAP   768                    // per-block staging (~184 expected hits, >40 sigma)

typedef unsigned long long u64;
typedef unsigned int u32;

// ---------------- K-1: zero the padded per-task candidate counters ----------------
__global__ __launch_bounds__(512) void k_zero(u32* __restrict__ ccnt) {
    for (int i = threadIdx.x; i < NTASK * CPAD; i += 512) ccnt[i] = 0;
}

// ---------------- K0: coalesced prefilter scan with per-block LDS aggregation ----------------
// Each block scans a contiguous chunk of conf [B,P,21] as float4. Hits (s>=T0) are
// staged in LDS with per-task local ranks; at the end, ONE global atomic per
// (block,task) reserves a contiguous range in the task's candidate list, and staged
// entries are flushed as contiguous runs. Order is irrelevant (k_nms sorts).
__global__ __launch_bounds__(256) void k_collect(const float* __restrict__ conf,
                                                 u64* __restrict__ cl,
                                                 u32* __restrict__ ccnt) {
    __shared__ u64 skey[STAGE_CAP];
    __shared__ u32 smeta[STAGE_CAP];      // task<<16 | lrank
    __shared__ u32 lcnt[NTASK];
    __shared__ u32 lbase[NTASK];
    __shared__ u32 ns;

    const int tid = threadIdx.x;
    for (int i = tid; i < NTASK; i += 256) lcnt[i] = 0;
    if (tid == 0) ns = 0;
    __syncthreads();

    const int start = blockIdx.x * CCHUNK;
    int end = start + CCHUNK; if (end > TOTAL4) end = TOTAL4;
    const float4* conf4 = (const float4*)conf;

    for (int t = start + tid; t < end; t += 256) {
        float4 v = conf4[t];
        float vv[4] = {v.x, v.y, v.z, v.w};
#pragma unroll
        for (int j = 0; j < 4; ++j) {
            float s = vv[j];
            if (s >= T0) {
                int e = 4 * t + j;
                int c = e % NUM_CLASSES;
                if (c == 0) continue;              // background
                int bp = e / NUM_CLASSES;          // b*P + p
                int b = bp / P;
                int p = bp - b * P;
                u32 task = (u32)(b * NCM1 + (c - 1));
                u32 lr = atomicAdd(&lcnt[task], 1u);
                u32 slot = atomicAdd(&ns, 1u);
                if (slot < STAGE_CAP) {
                    skey[slot] = ((u64)__float_as_uint(s) << 32) | (u32)(~(u32)p);
                    smeta[slot] = (task << 16) | lr;
                }
            }
        }
    }
    __syncthreads();

    // reserve contiguous ranges: one global atomic per (block, task-with-hits)
    for (int tsk = tid; tsk < NTASK; tsk += 256)
        if (lcnt[tsk]) lbase[tsk] = atomicAdd(&ccnt[tsk * CPAD], lcnt[tsk]);
    __syncthreads();

    // flush staged entries
    u32 n = ns; if (n > STAGE_CAP) n = STAGE_CAP;
    for (u32 i = tid; i < n; i += 256) {
        u32 m = smeta[i];
        u32 task = m >> 16, lr = m & 0xFFFFu;
        u32 pos = lbase[task] + lr;
        if (pos < CAND_CAP) cl[(size_t)task * CAND_CAP + pos] = skey[i];
    }
}

// ---------------- K1: per-(image,class) sort + NMS ----------------
__global__ __launch_bounds__(1024) void k_nms(
    const float* __restrict__ loc, const float* __restrict__ priors,
    const float* __restrict__ conf,
    const u64* __restrict__ cl, const u32* __restrict__ ccnt,
    float* __restrict__ dets, int* __restrict__ counts) {

    const int tid = threadIdx.x;
    const int task = blockIdx.x;            // 0..319
    const int b = task / NCM1, c0 = task - b * NCM1;

    __shared__ u64 cand[CAND_CAP];
    __shared__ float sx1[K_CAND], sy1[K_CAND], sx2[K_CAND], sy2[K_CAND];
    __shared__ float sar[K_CAND], ssc[K_CAND];
    __shared__ unsigned char sval[K_CAND];
    __shared__ u64 iou_mask[K_CAND][MASK_W];
    __shared__ u64 kept_w[MASK_W];
    __shared__ int s_cnt;
    __shared__ u32 hist[4][256];
    __shared__ u32 suf[256];
    __shared__ u32 s_cut, s_k, s_ncand;

    const u32 n = ccnt[task * CPAD];        // block-uniform
    u32 ncand;

    if (n >= K_CAND && n <= CAND_CAP) {
        // ---- fast path: prefilter list provably contains the exact top-400 ----
        const u64* src = cl + (size_t)task * CAND_CAP;
        for (int i = tid; i < CAND_CAP; i += 1024)
            cand[i] = ((u32)i < n) ? src[i] : 0ull;
        ncand = n;
        __syncthreads();
    } else {
        // ---- exact fallback: 4-round MSB radix select, strided conf reads ----
        const float* sp = conf + (size_t)b * P * NUM_CLASSES + (c0 + 1);
        u32 prefix = 0, k = K_CAND;
        const int wv = (tid >> 6) & 3;
        for (int round = 0; round < 4; ++round) {
            if (tid < 256) { hist[0][tid] = 0; hist[1][tid] = 0;
                             hist[2][tid] = 0; hist[3][tid] = 0; }
            __syncthreads();
            const int msb = 8 * round;
            const int dsh = 24 - msb;
            for (int p = tid; p < P; p += 1024) {
                u32 u = __float_as_uint(sp[(size_t)p * NUM_CLASSES]);
                bool match = (round == 0) || ((u >> (32 - msb)) == prefix);
                if (match) atomicAdd(&hist[wv][(u >> dsh) & 0xFF], 1u);
            }
            __syncthreads();
            if (tid < 256)
                suf[tid] = hist[0][tid] + hist[1][tid] + hist[2][tid] + hist[3][tid];
            __syncthreads();
            for (int off = 1; off < 256; off <<= 1) {
                u32 v = 0;
                if (tid < 256) v = suf[tid] + ((tid + off < 256) ? suf[tid + off] : 0u);
                __syncthreads();
                if (tid < 256) suf[tid] = v;
                __syncthreads();
            }
            if (tid < 256 && suf[tid] >= k && (tid == 255 || suf[tid + 1] < k)) {
                s_cut = (u32)tid;
                s_k = k - ((tid == 255) ? 0u : suf[tid + 1]);
            }
            __syncthreads();
            prefix = (prefix << 8) | s_cut;
            k = s_k;
            __syncthreads();
        }
        const u32 V = prefix;
        if (tid == 0) s_ncand = 0;
        __syncthreads();
        for (int p = tid; p < P; p += 1024) {
            u32 u = __float_as_uint(sp[(size_t)p * NUM_CLASSES]);
            if (u >= V) {
                u32 pos = atomicAdd(&s_ncand, 1u);
                if (pos < CAND_CAP) cand[pos] = ((u64)u << 32) | (u32)(~(u32)p);
            }
        }
        __syncthreads();
        ncand = min(s_ncand, (u32)CAND_CAP);
        for (u32 i = ncand + tid; i < CAND_CAP; i += 1024) cand[i] = 0ull;
        __syncthreads();
    }

    // ---- bitonic sort CAND_CAP descending (score desc, prior-idx asc) ----
    for (u32 ksz = 2; ksz <= CAND_CAP; ksz <<= 1) {
        for (u32 j = ksz >> 1; j > 0; j >>= 1) {
            if (tid < CAND_CAP / 2) {
                u32 i = 2 * tid - (tid & (j - 1));
                u32 ixj = i | j;
                u64 a = cand[i], c = cand[ixj];
                bool up = ((i & ksz) == 0);
                if (up ? (a < c) : (a > c)) { cand[i] = c; cand[ixj] = a; }
            }
            __syncthreads();
        }
    }

    // ---- decode top-400 candidate boxes (reference op order) ----
    for (int r = tid; r < K_CAND; r += 1024) {
        if ((u32)r < ncand) {
            u64 key = cand[r];
            u32 idx = ~(u32)key;
            float sc = __uint_as_float((u32)(key >> 32));
            float4 lc = ((const float4*)loc)[(size_t)b * P + idx];
            float4 pr = ((const float4*)priors)[idx];
            float cx = pr.x + lc.x * VAR0 * pr.z;
            float cy = pr.y + lc.y * VAR0 * pr.w;
            float w  = pr.z * expf(lc.z * VAR1);
            float h  = pr.w * expf(lc.w * VAR1);
            float x1 = cx - w * 0.5f, y1 = cy - h * 0.5f;
            float x2 = x1 + w, y2 = y1 + h;
            sx1[r] = x1; sy1[r] = y1; sx2[r] = x2; sy2[r] = y2;
            sar[r] = (x2 - x1) * (y2 - y1);
            ssc[r] = sc;
            sval[r] = (sc > CONF_THRESH) ? 1 : 0;
        } else {
            sx1[r] = 0; sy1[r] = 0; sx2[r] = 0; sy2[r] = 0;
            sar[r] = 0; ssc[r] = 0; sval[r] = 0;
        }
    }
    __syncthreads();

    // ---- 400x400 IoU>thresh bitmask ----
    for (int t = tid; t < K_CAND * MASK_W; t += 1024) {
        int i = t / MASK_W, w = t - i * MASK_W;
        float ix1 = sx1[i], iy1 = sy1[i], ix2 = sx2[i], iy2 = sy2[i], iar = sar[i];
        u64 m = 0;
        int j0 = w * 64;
        int jend = j0 + 64; if (jend > K_CAND) jend = K_CAND;
        for (int j = j0; j < jend; ++j) {
            float xx1 = fmaxf(ix1, sx1[j]);
            float yy1 = fmaxf(iy1, sy1[j]);
            float xx2 = fminf(ix2, sx2[j]);
            float yy2 = fminf(iy2, sy2[j]);
            float iw = fmaxf(xx2 - xx1, 0.0f);
            float ih = fmaxf(yy2 - yy1, 0.0f);
            float inter = iw * ih;
            float uni = iar + sar[j] - inter;
            float iou = inter / fmaxf(uni, 1e-9f);
            if (iou > NMS_THRESH) m |= (1ull << (j - j0));
        }
        iou_mask[i][w] = m;
    }
    __syncthreads();

    // ---- greedy NMS, single wave; lane l holds kept-word l ----
    if (tid < 64) {
        int l = tid;
        u64 kw = 0;
        int cnt = 0;
        for (int i = 0; i < K_CAND; ++i) {
            if (!sval[i]) break;                       // scores desc => valid is a prefix
            u64 mm = (l < MASK_W) ? iou_mask[i][l] : 0ull;
            bool sup = __any((kw & mm) != 0ull);
            if (!sup && cnt < TOP_K) {
                if (l == (i >> 6)) kw |= (1ull << (i & 63));
                ++cnt;
                if (cnt >= TOP_K) break;
            }
        }
        if (l < MASK_W) kept_w[l] = kw;
        if (l == 0) s_cnt = cnt;
    }
    __syncthreads();

    // ---- compact kept (score order == index order) into dets ----
    for (int i = tid; i < K_CAND; i += 1024) {
        u64 w = kept_w[i >> 6];
        if ((w >> (i & 63)) & 1ull) {
            int rank = 0;
            for (int q = 0; q < (i >> 6); ++q) rank += __popcll(kept_w[q]);
            rank += __popcll(w & ((1ull << (i & 63)) - 1ull));
            float* dst = dets + ((size_t)task * TOP_K + rank) * 6;
            dst[0] = sx1[i]; dst[1] = sy1[i]; dst[2] = sx2[i]; dst[3] = sy2[i];
            dst[4] = ssc[i]; dst[5] = (float)(c0 + 1);
        }
    }
    if (tid == 0) counts[task] = s_cnt;
}

// ---------------- K2: per-image global sort of 4000 slots -> output ----------------
#define NSLOT (NCM1 * TOP_K)         // 4000
#define NSORT 4096
#define OUTR  (NUM_CLASSES * TOP_K)  // 4200

__global__ __launch_bounds__(1024) void k_final(const float* __restrict__ dets,
                                                const int* __restrict__ counts,
                                                float* __restrict__ out) {
    const int b = blockIdx.x, tid = threadIdx.x;
    __shared__ u64 key[NSORT];

    for (int f = tid; f < NSORT; f += 1024) {
        u64 kk = 0;
        if (f < NSLOT) {
            int c0 = f / TOP_K, slot = f - c0 * TOP_K;
            if (slot < counts[b * NCM1 + c0]) {
                float sc = dets[((size_t)(b * NCM1 + c0) * TOP_K + slot) * 6 + 4];
                kk = ((u64)__float_as_uint(sc) << 32) | (u32)(~(u32)f);
            }
        }
        key[f] = kk;
    }
    __syncthreads();

    for (u32 ksz = 2; ksz <= NSORT; ksz <<= 1) {
        for (u32 j = ksz >> 1; j > 0; j >>= 1) {
            for (u32 t = tid; t < NSORT / 2; t += 1024) {
                u32 i = 2 * t - (t & (j - 1));
                u32 ixj = i | j;
                u64 a = key[i], c = key[ixj];
                bool up = ((i & ksz) == 0);
                if (up ? (a < c) : (a > c)) { key[i] = c; key[ixj] = a; }
            }
            __syncthreads();
        }
    }

    for (int r = tid; r < OUTR; r += 1024) {
        float o0 = 0, o1 = 0, o2 = 0, o3 = 0, o4 = 0, o5 = 0;
        if (r < NSORT) {
            u64 kk = key[r];
            if (kk) {
                int f = (int)(~(u32)kk);
                int c0 = f / TOP_K, slot = f - c0 * TOP_K;
                const float* src = dets + ((size_t)(b * NCM1 + c0) * TOP_K + slot) * 6;
                o0 = src[0]; o1 = src[1]; o2 = src[2];
                o3 = src[3]; o4 = src[4]; o5 = src[5];
            }
        }
        float* dst = out + ((size_t)b * OUTR + r) * 6;
        dst[0] = o0; dst[1] = o1; dst[2] = o2; dst[3] = o3; dst[4] = o4; dst[5] = o5;
    }
}

extern "C" void kernel_launch(void* const* d_in, const int* in_sizes, int n_in,
                              void* d_out, int out_size, void* d_ws, size_t ws_size,
                              hipStream_t stream) {
    const float* loc    = (const float*)d_in[0];
    const float* conf   = (const float*)d_in[1];
    const float* priors = (const float*)d_in[2];
    float* out = (float*)d_out;

    size_t off = 0;
    u32* ccnt = (u32*)((char*)d_ws + off);
    off += (size_t)NTASK * CPAD * sizeof(u32);              // 20 KB (padded counters)
    off = (off + 255) & ~(size_t)255;
    u64* cl = (u64*)((char*)d_ws + off);
    off += (size_t)NTASK * CAND_CAP * sizeof(u64);          // 2.62 MB
    float* dets = (float*)((char*)d_ws + off);
    off += (size_t)NTASK * TOP_K * 6 * sizeof(float);       // 1.54 MB
    int* counts = (int*)((char*)d_ws + off);

    k_zero<<<1, 512, 0, stream>>>(ccnt);
    k_collect<<<CBLK, 256, 0, stream>>>(conf, cl, ccnt);
    k_nms<<<NTASK, 1024, 0, stream>>>(loc, priors, conf, cl, ccnt, dets, counts);
    k_final<<<BS, 1024, 0, stream>>>(dets, counts, out);
}

// Round 13
// 273.017 us; speedup vs baseline: 2.7927x; 1.2982x over previous
//
// v12 (identical to v11; resubmitted after container infra failure)
#include <hip/hip_runtime.h>
#include <hip/hip_bf16.h>
#include <math.h>

#define NUM_CLASSES 21
#define NCM1        20      // classes minus background
#define TOP_K       200
#define K_CAND      400
#define NMS_THRESH  0.45f
#define CONF_THRESH 0.01f
#define VAR0        0.1f
#define VAR1        0.2f
#define P           24564
#define BS          16

#define MASK_W      7       // ceil(400/64)
#define CAND_CAP    1024
#define T0          0.97f   // prefilter threshold; exact-top400 guaranteed when
                            // 400 <= count(s>=T0) <= 1024, else exact fallback path

#define NTASK       (BS * NCM1)            // 320
#define CPAD        16                     // ccnt stride in u32 = 64B (one cache line per counter)
#define TOTAL4      (BS * P * NUM_CLASSES / 4)   // 2,063,376 (divides exactly)
#define CBLK        1280                   // collect blocks
#define CCHUNK      ((TOTAL4 + CBLK - 1) / CBLK) // float4s per collect block
#define STAGE_CAP   768                    // per-block staging (~184 expected hits, >40 sigma)

typedef unsigned long long u64;
typedef unsigned int u32;

// ---------------- K-1: zero the padded per-task candidate counters ----------------
__global__ __launch_bounds__(512) void k_zero(u32* __restrict__ ccnt) {
    for (int i = threadIdx.x; i < NTASK * CPAD; i += 512) ccnt[i] = 0;
}

// ---------------- K0: coalesced prefilter scan with per-block LDS aggregation ----------------
__global__ __launch_bounds__(256) void k_collect(const float* __restrict__ conf,
                                                 u64* __restrict__ cl,
                                                 u32* __restrict__ ccnt) {
    __shared__ u64 skey[STAGE_CAP];
    __shared__ u32 smeta[STAGE_CAP];      // task<<16 | lrank
    __shared__ u32 lcnt[NTASK];
    __shared__ u32 lbase[NTASK];
    __shared__ u32 ns;

    const int tid = threadIdx.x;
    for (int i = tid; i < NTASK; i += 256) lcnt[i] = 0;
    if (tid == 0) ns = 0;
    __syncthreads();

    const int start = blockIdx.x * CCHUNK;
    int end = start + CCHUNK; if (end > TOTAL4) end = TOTAL4;
    const float4* conf4 = (const float4*)conf;

    for (int t = start + tid; t < end; t += 256) {
        float4 v = conf4[t];
        float vv[4] = {v.x, v.y, v.z, v.w};
#pragma unroll
        for (int j = 0; j < 4; ++j) {
            float s = vv[j];
            if (s >= T0) {
                int e = 4 * t + j;
                int c = e % NUM_CLASSES;
                if (c == 0) continue;              // background
                int bp = e / NUM_CLASSES;          // b*P + p
                int b = bp / P;
                int p = bp - b * P;
                u32 task = (u32)(b * NCM1 + (c - 1));
                u32 lr = atomicAdd(&lcnt[task], 1u);
                u32 slot = atomicAdd(&ns, 1u);
                if (slot < STAGE_CAP) {
                    skey[slot] = ((u64)__float_as_uint(s) << 32) | (u32)(~(u32)p);
                    smeta[slot] = (task << 16) | lr;
                }
            }
        }
    }
    __syncthreads();

    // reserve contiguous ranges: one global atomic per (block, task-with-hits)
    for (int tsk = tid; tsk < NTASK; tsk += 256)
        if (lcnt[tsk]) lbase[tsk] = atomicAdd(&ccnt[tsk * CPAD], lcnt[tsk]);
    __syncthreads();

    // flush staged entries
    u32 n = ns; if (n > STAGE_CAP) n = STAGE_CAP;
    for (u32 i = tid; i < n; i += 256) {
        u32 m = smeta[i];
        u32 task = m >> 16, lr = m & 0xFFFFu;
        u32 pos = lbase[task] + lr;
        if (pos < CAND_CAP) cl[(size_t)task * CAND_CAP + pos] = skey[i];
    }
}

// ---------------- K1: per-(image,class) sort + NMS ----------------
__global__ __launch_bounds__(1024) void k_nms(
    const float* __restrict__ loc, const float* __restrict__ priors,
    const float* __restrict__ conf,
    const u64* __restrict__ cl, const u32* __restrict__ ccnt,
    float* __restrict__ dets, int* __restrict__ counts) {

    const int tid = threadIdx.x;
    const int task = blockIdx.x;            // 0..319
    const int b = task / NCM1, c0 = task - b * NCM1;

    __shared__ u64 cand[CAND_CAP];
    __shared__ float4 sbox[K_CAND];         // x1,y1,x2,y2
    __shared__ float sar[K_CAND], ssc[K_CAND];
    __shared__ unsigned char sval[K_CAND];
    __shared__ u64 iou_mask[K_CAND][MASK_W];
    __shared__ u64 kept_w[MASK_W];
    __shared__ int s_cnt;
    __shared__ u32 hist[4][256];
    __shared__ u32 suf[256];
    __shared__ u32 s_cut, s_k, s_ncand;

    const u32 n = ccnt[task * CPAD];        // block-uniform
    u32 ncand;

    if (n >= K_CAND && n <= CAND_CAP) {
        // ---- fast path: prefilter list provably contains the exact top-400 ----
        const u64* src = cl + (size_t)task * CAND_CAP;
        for (int i = tid; i < CAND_CAP; i += 1024)
            cand[i] = ((u32)i < n) ? src[i] : 0ull;
        ncand = n;
        __syncthreads();
    } else {
        // ---- exact fallback: 4-round MSB radix select, strided conf reads ----
        const float* sp = conf + (size_t)b * P * NUM_CLASSES + (c0 + 1);
        u32 prefix = 0, k = K_CAND;
        const int wv = (tid >> 6) & 3;
        for (int round = 0; round < 4; ++round) {
            if (tid < 256) { hist[0][tid] = 0; hist[1][tid] = 0;
                             hist[2][tid] = 0; hist[3][tid] = 0; }
            __syncthreads();
            const int msb = 8 * round;
            const int dsh = 24 - msb;
            for (int p = tid; p < P; p += 1024) {
                u32 u = __float_as_uint(sp[(size_t)p * NUM_CLASSES]);
                bool match = (round == 0) || ((u >> (32 - msb)) == prefix);
                if (match) atomicAdd(&hist[wv][(u >> dsh) & 0xFF], 1u);
            }
            __syncthreads();
            if (tid < 256)
                suf[tid] = hist[0][tid] + hist[1][tid] + hist[2][tid] + hist[3][tid];
            __syncthreads();
            for (int off = 1; off < 256; off <<= 1) {
                u32 v = 0;
                if (tid < 256) v = suf[tid] + ((tid + off < 256) ? suf[tid + off] : 0u);
                __syncthreads();
                if (tid < 256) suf[tid] = v;
                __syncthreads();
            }
            if (tid < 256 && suf[tid] >= k && (tid == 255 || suf[tid + 1] < k)) {
                s_cut = (u32)tid;
                s_k = k - ((tid == 255) ? 0u : suf[tid + 1]);
            }
            __syncthreads();
            prefix = (prefix << 8) | s_cut;
            k = s_k;
            __syncthreads();
        }
        const u32 V = prefix;
        if (tid == 0) s_ncand = 0;
        __syncthreads();
        for (int p = tid; p < P; p += 1024) {
            u32 u = __float_as_uint(sp[(size_t)p * NUM_CLASSES]);
            if (u >= V) {
                u32 pos = atomicAdd(&s_ncand, 1u);
                if (pos < CAND_CAP) cand[pos] = ((u64)u << 32) | (u32)(~(u32)p);
            }
        }
        __syncthreads();
        ncand = min(s_ncand, (u32)CAND_CAP);
        for (u32 i = ncand + tid; i < CAND_CAP; i += 1024) cand[i] = 0ull;
        __syncthreads();
    }

    // ---- bitonic sort CAND_CAP descending (score desc, prior-idx asc) ----
    for (u32 ksz = 2; ksz <= CAND_CAP; ksz <<= 1) {
        for (u32 j = ksz >> 1; j > 0; j >>= 1) {
            if (tid < CAND_CAP / 2) {
                u32 i = 2 * tid - (tid & (j - 1));
                u32 ixj = i | j;
                u64 a = cand[i], c = cand[ixj];
                bool up = ((i & ksz) == 0);
                if (up ? (a < c) : (a > c)) { cand[i] = c; cand[ixj] = a; }
            }
            __syncthreads();
        }
    }

    // ---- decode top-400 candidate boxes (reference op order) ----
    for (int r = tid; r < K_CAND; r += 1024) {
        if ((u32)r < ncand) {
            u64 key = cand[r];
            u32 idx = ~(u32)key;
            float sc = __uint_as_float((u32)(key >> 32));
            float4 lc = ((const float4*)loc)[(size_t)b * P + idx];
            float4 pr = ((const float4*)priors)[idx];
            float cx = pr.x + lc.x * VAR0 * pr.z;
            float cy = pr.y + lc.y * VAR0 * pr.w;
            float w  = pr.z * expf(lc.z * VAR1);
            float h  = pr.w * expf(lc.w * VAR1);
            float x1 = cx - w * 0.5f, y1 = cy - h * 0.5f;
            float x2 = x1 + w, y2 = y1 + h;
            sbox[r] = make_float4(x1, y1, x2, y2);
            sar[r] = (x2 - x1) * (y2 - y1);
            ssc[r] = sc;
            sval[r] = (sc > CONF_THRESH) ? 1 : 0;
        } else {
            sbox[r] = make_float4(0.f, 0.f, 0.f, 0.f);
            sar[r] = 0.f; ssc[r] = 0.f; sval[r] = 0;
        }
    }
    __syncthreads();

    // ---- 400x400 IoU>thresh bitmask: wave-per-strip, boxes in registers, ballot ----
    // Wave q (of 16): strip = q&7 (0..6 active), i-half = q>>3. Lane l owns box
    // j = strip*64+l in registers; loop over i reads sbox[i]/sar[i] as same-address
    // broadcasts (conflict-free); mask word built with __ballot.
    {
        const int wave = tid >> 6, lane = tid & 63;
        const int strip = wave & 7;
        const int ihalf = wave >> 3;
        if (strip < MASK_W) {
            const int j = strip * 64 + lane;
            float4 bj = make_float4(0.f, 0.f, 0.f, 0.f);
            float aj = 0.f;
            if (j < K_CAND) { bj = sbox[j]; aj = sar[j]; }
            const int i0 = ihalf * (K_CAND / 2);
            for (int i = i0; i < i0 + K_CAND / 2; ++i) {
                float4 bi = sbox[i];               // broadcast
                float ai = sar[i];                 // broadcast
                float xx1 = fmaxf(bi.x, bj.x);
                float yy1 = fmaxf(bi.y, bj.y);
                float xx2 = fminf(bi.z, bj.z);
                float yy2 = fminf(bi.w, bj.w);
                float iw = fmaxf(xx2 - xx1, 0.0f);
                float ih = fmaxf(yy2 - yy1, 0.0f);
                float inter = iw * ih;
                float uni = ai + aj - inter;
                float iou = inter / fmaxf(uni, 1e-9f);
                u64 m = __ballot(iou > NMS_THRESH);
                if (lane == 0) iou_mask[i][strip] = m;
            }
        }
    }
    __syncthreads();

    // ---- greedy NMS, single wave; lane l holds kept-word l ----
    if (tid < 64) {
        int l = tid;
        u64 kw = 0;
        int cnt = 0;
        for (int i = 0; i < K_CAND; ++i) {
            if (!sval[i]) break;                       // scores desc => valid is a prefix
            u64 mm = (l < MASK_W) ? iou_mask[i][l] : 0ull;
            bool sup = __any((kw & mm) != 0ull);
            if (!sup && cnt < TOP_K) {
                if (l == (i >> 6)) kw |= (1ull << (i & 63));
                ++cnt;
                if (cnt >= TOP_K) break;
            }
        }
        if (l < MASK_W) kept_w[l] = kw;
        if (l == 0) s_cnt = cnt;
    }
    __syncthreads();

    // ---- compact kept (score order == index order) into dets ----
    for (int i = tid; i < K_CAND; i += 1024) {
        u64 w = kept_w[i >> 6];
        if ((w >> (i & 63)) & 1ull) {
            int rank = 0;
            for (int q = 0; q < (i >> 6); ++q) rank += __popcll(kept_w[q]);
            rank += __popcll(w & ((1ull << (i & 63)) - 1ull));
            float4 bx = sbox[i];
            float* dst = dets + ((size_t)task * TOP_K + rank) * 6;
            dst[0] = bx.x; dst[1] = bx.y; dst[2] = bx.z; dst[3] = bx.w;
            dst[4] = ssc[i]; dst[5] = (float)(c0 + 1);
        }
    }
    if (tid == 0) counts[task] = s_cnt;
}

// ---------------- K2: per-image global sort of 4000 slots -> output ----------------
#define NSLOT (NCM1 * TOP_K)         // 4000
#define NSORT 4096
#define OUTR  (NUM_CLASSES * TOP_K)  // 4200

__global__ __launch_bounds__(1024) void k_final(const float* __restrict__ dets,
                                                const int* __restrict__ counts,
                                                float* __restrict__ out) {
    const int b = blockIdx.x, tid = threadIdx.x;
    __shared__ u64 key[NSORT];

    for (int f = tid; f < NSORT; f += 1024) {
        u64 kk = 0;
        if (f < NSLOT) {
            int c0 = f / TOP_K, slot = f - c0 * TOP_K;
            if (slot < counts[b * NCM1 + c0]) {
                float sc = dets[((size_t)(b * NCM1 + c0) * TOP_K + slot) * 6 + 4];
                kk = ((u64)__float_as_uint(sc) << 32) | (u32)(~(u32)f);
            }
        }
        key[f] = kk;
    }
    __syncthreads();

    for (u32 ksz = 2; ksz <= NSORT; ksz <<= 1) {
        for (u32 j = ksz >> 1; j > 0; j >>= 1) {
            for (u32 t = tid; t < NSORT / 2; t += 1024) {
                u32 i = 2 * t - (t & (j - 1));
                u32 ixj = i | j;
                u64 a = key[i], c = key[ixj];
                bool up = ((i & ksz) == 0);
                if (up ? (a < c) : (a > c)) { key[i] = c; key[ixj] = a; }
            }
            __syncthreads();
        }
    }

    for (int r = tid; r < OUTR; r += 1024) {
        float o0 = 0, o1 = 0, o2 = 0, o3 = 0, o4 = 0, o5 = 0;
        if (r < NSORT) {
            u64 kk = key[r];
            if (kk) {
                int f = (int)(~(u32)kk);
                int c0 = f / TOP_K, slot = f - c0 * TOP_K;
                const float* src = dets + ((size_t)(b * NCM1 + c0) * TOP_K + slot) * 6;
                o0 = src[0]; o1 = src[1]; o2 = src[2];
                o3 = src[3]; o4 = src[4]; o5 = src[5];
            }
        }
        float* dst = out + ((size_t)b * OUTR + r) * 6;
        dst[0] = o0; dst[1] = o1; dst[2] = o2; dst[3] = o3; dst[4] = o4; dst[5] = o5;
    }
}

extern "C" void kernel_launch(void* const* d_in, const int* in_sizes, int n_in,
                              void* d_out, int out_size, void* d_ws, size_t ws_size,
                              hipStream_t stream) {
    const float* loc    = (const float*)d_in[0];
    const float* conf   = (const float*)d_in[1];
    const float* priors = (const float*)d_in[2];
    float* out = (float*)d_out;

    size_t off = 0;
    u32* ccnt = (u32*)((char*)d_ws + off);
    off += (size_t)NTASK * CPAD * sizeof(u32);              // 20 KB (padded counters)
    off = (off + 255) & ~(size_t)255;
    u64* cl = (u64*)((char*)d_ws + off);
    off += (size_t)NTASK * CAND_CAP * sizeof(u64);          // 2.62 MB
    float* dets = (float*)((char*)d_ws + off);
    off += (size_t)NTASK * TOP_K * 6 * sizeof(float);       // 1.54 MB
    int* counts = (int*)((char*)d_ws + off);

    k_zero<<<1, 512, 0, stream>>>(ccnt);
    k_collect<<<CBLK, 256, 0, stream>>>(conf, cl, ccnt);
    k_nms<<<NTASK, 1024, 0, stream>>>(loc, priors, conf, cl, ccnt, dets, counts);
    k_final<<<BS, 1024, 0, stream>>>(dets, counts, out);
}